// Round 11
// baseline (215.399 us; speedup 1.0000x reference)
//
#include <hip/hip_runtime.h>

#define MWIN 2048
#define HH 8

typedef _Float16 half8 __attribute__((ext_vector_type(8)));
typedef _Float16 half4 __attribute__((ext_vector_type(4)));
typedef float f32x4 __attribute__((ext_vector_type(4)));

// XCD-chunked window swizzle: 3x3 pooling neighbors (w +-1, +-32) stay in the
// same XCD L2 for both producer and consumer kernels.
__device__ __forceinline__ int win_swz(int bid) {
    return (bid & 7) * 256 + (bid >> 3);
}

// ---- weight prep: fragmentize Wqkv/Wproj fp32 -> MFMA-fragment fp16.
__global__ __launch_bounds__(256) void k_prep_w(const float* __restrict__ Wqkv,
                                                const float* __restrict__ Wproj,
                                                _Float16* __restrict__ fq,
                                                _Float16* __restrict__ fp) {
    int tid = blockIdx.x * 256 + threadIdx.x;
    const float* src;
    _Float16* dst;
    if (tid < 6144) { src = Wqkv; dst = fq; }
    else {
        tid -= 6144;
        if (tid >= 2048) return;
        src = Wproj; dst = fp;
    }
    int lane = tid & 63, r = tid >> 6;
    int ct = r & 3, ks = (r >> 2) & 3, cg = r >> 4;
    int m = lane & 15, q = lane >> 4;
    const float* s_ = src + (size_t)(cg * 64 + ct * 16 + m) * 128 + q * 8 + ks * 32;
    float4 f0 = *(const float4*)s_;
    float4 f1 = *(const float4*)(s_ + 4);
    half8 h;
    h[0] = (_Float16)f0.x; h[1] = (_Float16)f0.y; h[2] = (_Float16)f0.z; h[3] = (_Float16)f0.w;
    h[4] = (_Float16)f1.x; h[5] = (_Float16)f1.y; h[6] = (_Float16)f1.z; h[7] = (_Float16)f1.w;
    *(half8*)(dst + (size_t)tid * 8) = h;
}

// ---- per-window fused QKV GEMM + kv/s reduction ----
// ROUND-11: LDS lifetime overlay. Col-tile mapping ctg = j*8 + h: j=0 emits
// ALL of q (xs already dead: frags live in regs), j=1 all k, j=2 all v.
// One 36.9KB buffer serves xs -> q_lds -> kT/vT in sequence, barrier-
// separated: LDS 49.9 -> 36.9 KB => 4 blocks/CU (32 waves, max occupancy).
// launch_bounds (512,8) caps VGPR at 64 (prior compiles of this structure:
// 44-52). ks-outer inner loop keeps one B-fragment live at a time.
__global__ __launch_bounds__(512, 8) void k_qkv_win(const float* __restrict__ x,
                                                    const half8* __restrict__ fq,
                                                    const int* __restrict__ offsets,
                                                    const int* __restrict__ counts,
                                                    _Float16* __restrict__ q_h,
                                                    float* __restrict__ kv_t,
                                                    float* __restrict__ s) {
    // 36864B overlay buffer:
    //   phase A: xs[48][136]      (13056B)  stage -> frag-read
    //   phase Q: q_lds[48][136]   (13056B)  j0 write -> global store
    //   phase KV: kT[8][16][72] @0, vT[8][16][72] @9216 halfs (36864B)
    __shared__ __attribute__((aligned(16))) _Float16 ubuf[18432];
    _Float16 (*xs)[136]    = (_Float16(*)[136])ubuf;
    _Float16 (*q_lds)[136] = (_Float16(*)[136])ubuf;
    _Float16 (*kT)[16][72] = (_Float16(*)[16][72])ubuf;
    _Float16 (*vT)[16][72] = (_Float16(*)[16][72])(ubuf + 9216);

    int w = win_swz(blockIdx.x);
    int off = offsets[w], cnt = counts[w];
    int tid = threadIdx.x;

    // ---- phase A: cooperative coalesced stage of x (48 rows x 32 float4) ----
    #pragma unroll
    for (int it = 0; it < 3; ++it) {
        int j = it * 512 + tid;
        int row = j >> 5, c4 = j & 31;
        int sr = row < cnt ? row : cnt - 1;
        float4 f = *(const float4*)(x + (size_t)(off + sr) * 128 + c4 * 4);
        half4 hv;
        hv[0] = (_Float16)f.x; hv[1] = (_Float16)f.y;
        hv[2] = (_Float16)f.z; hv[3] = (_Float16)f.w;
        *(half4*)&xs[row][c4 * 4] = hv;
    }
    __syncthreads();                       // bar1: xs ready

    int h = tid >> 6, lane = tid & 63;
    int m = lane & 15, q = lane >> 4;

    // A fragments from LDS into registers
    half8 a[3][4];
    #pragma unroll
    for (int rt = 0; rt < 3; ++rt)
        #pragma unroll
        for (int ks = 0; ks < 4; ++ks)
            a[rt][ks] = *(const half8*)&xs[rt * 16 + m][q * 8 + ks * 32];
    __syncthreads();                       // bar2: xs dead, buffer reusable

    // ---- GEMM: j=0 -> q (all waves), j=1 -> k, j=2 -> v ----
    #pragma unroll
    for (int j = 0; j < 3; ++j) {
        int ctg = j * 8 + h;
        int cg = ctg >> 2, ctl = ctg & 3;
        f32x4 acc0 = {}, acc1 = {}, acc2 = {};
        #pragma unroll
        for (int ks = 0; ks < 4; ++ks) {
            half8 bfr = fq[((size_t)cg * 16 + ks * 4 + ctl) * 64 + lane];
            acc0 = __builtin_amdgcn_mfma_f32_16x16x32_f16(a[0][ks], bfr, acc0, 0, 0, 0);
            acc1 = __builtin_amdgcn_mfma_f32_16x16x32_f16(a[1][ks], bfr, acc1, 0, 0, 0);
            acc2 = __builtin_amdgcn_mfma_f32_16x16x32_f16(a[2][ks], bfr, acc2, 0, 0, 0);
        }
        if (j == 0) {
            // q: relu, row-major into q_lds (overlay; xs dead)
            #pragma unroll
            for (int reg = 0; reg < 4; ++reg) {
                q_lds[q * 4 + reg][h * 16 + m]      = (_Float16)fmaxf(acc0[reg], 0.f);
                q_lds[16 + q * 4 + reg][h * 16 + m] = (_Float16)fmaxf(acc1[reg], 0.f);
                q_lds[32 + q * 4 + reg][h * 16 + m] = (_Float16)fmaxf(acc2[reg], 0.f);
            }
            __syncthreads();               // bar3: q_lds complete
            // relu'd q rows -> global (coalesced half8)
            #pragma unroll
            for (int it = 0; it < 2; ++it) {
                int idx = it * 512 + tid;
                int row = idx >> 4, c8 = idx & 15;
                if (row < cnt)
                    *(half8*)(q_h + (size_t)(off + row) * 128 + c8 * 8) =
                        *(const half8*)&q_lds[row][c8 * 8];
            }
            __syncthreads();               // bar4: q_lds dead, kT/vT may write
        } else if (j == 1) {
            // k: relu + zero rows >= cnt, transposed kT[h][d][p]
            #pragma unroll
            for (int rt = 0; rt < 3; ++rt) {
                f32x4 acc = rt == 0 ? acc0 : (rt == 1 ? acc1 : acc2);
                int p0 = rt * 16 + q * 4;
                half4 hv;
                #pragma unroll
                for (int reg = 0; reg < 4; ++reg)
                    hv[reg] = (_Float16)((p0 + reg < cnt) ? fmaxf(acc[reg], 0.f) : 0.f);
                *(half4*)&kT[h][m][p0] = hv;
            }
            // wave-local zero-fill of kT[h] p 48..63
            {
                int zd = lane >> 2, zp = 48 + (lane & 3) * 4;
                *(half4*)&kT[h][zd][zp] = (half4){};
            }
        } else {
            // v: transposed vT[h][e][p]
            #pragma unroll
            for (int rt = 0; rt < 3; ++rt) {
                f32x4 acc = rt == 0 ? acc0 : (rt == 1 ? acc1 : acc2);
                int p0 = rt * 16 + q * 4;
                half4 hv;
                #pragma unroll
                for (int reg = 0; reg < 4; ++reg) hv[reg] = (_Float16)acc[reg];
                *(half4*)&vT[h][m][p0] = hv;
            }
            {
                int zd = lane >> 2, zp = 48 + (lane & 3) * 4;
                *(half4*)&vT[h][zd][zp] = (half4){};
            }
        }
    }

    // ---- kv = K^T V, s = K^T 1 via MFMA; wave h = head h (wave-local LDS) ----
    half8 a1 = *(const half8*)&kT[h][m][q * 8];
    half8 a2 = *(const half8*)&kT[h][m][32 + q * 8];
    half8 b1 = *(const half8*)&vT[h][m][q * 8];
    half8 b2 = *(const half8*)&vT[h][m][32 + q * 8];
    half8 ones;
    #pragma unroll
    for (int i = 0; i < 8; ++i) ones[i] = (_Float16)1.0f;
    f32x4 kva = {};
    kva = __builtin_amdgcn_mfma_f32_16x16x32_f16(a1, b1, kva, 0, 0, 0);
    kva = __builtin_amdgcn_mfma_f32_16x16x32_f16(a2, b2, kva, 0, 0, 0);
    f32x4 sa4 = {};
    sa4 = __builtin_amdgcn_mfma_f32_16x16x32_f16(a1, ones, sa4, 0, 0, 0);
    sa4 = __builtin_amdgcn_mfma_f32_16x16x32_f16(a2, ones, sa4, 0, 0, 0);
    *(f32x4*)(kv_t + (((size_t)(w * HH + h)) << 8) + m * 16 + q * 4) = kva;
    if (m == 0)
        *(f32x4*)(s + (((size_t)(w * HH + h)) << 4) + q * 4) = sa4;
}

// ---------------- fused attn + 3x3 pool + output projection ----------------
// (unchanged from round 10 so the qkv delta is attributable)
__global__ __launch_bounds__(512) void k_attn_proj(const _Float16* __restrict__ q_h,
                                                   const float* __restrict__ kv_t,
                                                   const float* __restrict__ s,
                                                   const half8* __restrict__ fp,
                                                   const float* __restrict__ bproj,
                                                   const int* __restrict__ offsets,
                                                   const int* __restrict__ counts,
                                                   float* __restrict__ out) {
    __shared__ _Float16 q_s[48][136];
    __shared__ _Float16 y_t[48][136];
    __shared__ float o_t[16][132];
    int w = win_swz(blockIdx.x);
    int h = threadIdx.x >> 6;
    int lane = threadIdx.x & 63;
    int col = lane & 15;
    int kq = lane >> 4;
    int off = offsets[w], cnt = counts[w];
    bool klive = kq < 2;
    int koff = (kq & 1) * 8;
    int tid = threadIdx.x;

    // coalesced stage of q rows (clamped at cnt-1 so attention needs no clamp)
    #pragma unroll
    for (int it = 0; it < 2; ++it) {
        int j = it * 512 + tid;
        int row = j >> 4, c8 = j & 15;
        if (row < 48) {
            int sr = row < cnt ? row : cnt - 1;
            *(half8*)&q_s[row][c8 * 8] =
                *(const half8*)(q_h + (size_t)(off + sr) * 128 + c8 * 8);
        }
    }

    // 3x3 pool into fp32 regs (overlaps the q staging; no barrier needed yet)
    int b = w >> 10, yy = (w >> 5) & 31, xx = w & 31;
    f32x4 k0 = {}, k1 = {}, s0 = {}, s1 = {};
    if (klive) {
        #pragma unroll
        for (int dy = -1; dy <= 1; ++dy)
            #pragma unroll
            for (int dx = -1; dx <= 1; ++dx) {
                int ny = yy + dy, nx = xx + dx;
                if (ny < 0 || ny >= 32 || nx < 0 || nx >= 32) continue;
                int nw = (b << 10) | (ny << 5) | nx;
                const float* kb = kv_t + (((size_t)(nw * HH + h)) << 8) + col * 16 + koff;
                k0 += *(const f32x4*)kb;
                k1 += *(const f32x4*)(kb + 4);
                const float* sb = s + (((size_t)(nw * HH + h)) << 4) + koff;
                s0 += *(const f32x4*)sb;
                s1 += *(const f32x4*)(sb + 4);
            }
    }
    half8 a_kv, a_s;
    #pragma unroll
    for (int i = 0; i < 4; ++i) {
        a_kv[i] = (_Float16)k0[i]; a_kv[4 + i] = (_Float16)k1[i];
        a_s[i]  = (_Float16)s0[i]; a_s[4 + i]  = (_Float16)s1[i];
    }
    __syncthreads();   // q_s ready

    #pragma unroll
    for (int c = 0; c < 3; ++c) {
        int p = c * 16 + col;
        half8 b_q = *(const half8*)&q_s[p][h * 16 + koff];
        f32x4 acc = {};
        acc = __builtin_amdgcn_mfma_f32_16x16x32_f16(a_kv, b_q, acc, 0, 0, 0);
        f32x4 accs = {};
        accs = __builtin_amdgcn_mfma_f32_16x16x32_f16(a_s, b_q, accs, 0, 0, 0);
        float zinv = 1.f / (accs[0] + 1e-6f);
        half4 yo;
        #pragma unroll
        for (int i = 0; i < 4; ++i) yo[i] = (_Float16)(acc[i] * zinv);
        *(half4*)&y_t[p][h * 16 + kq * 4] = yo;
    }
    __syncthreads();

    // projection: wave h owns output col-tile h; one 16-row band per step
    int m = col, q = kq;
    int cg = h >> 2, ctl = h & 3;
    half8 bfr[4];
    #pragma unroll
    for (int ks = 0; ks < 4; ++ks)
        bfr[ks] = fp[((size_t)cg * 16 + ks * 4 + ctl) * 64 + lane];
    float bv = bproj[h * 16 + m];
    #pragma unroll
    for (int rt = 0; rt < 3; ++rt) {
        f32x4 acc = (f32x4){bv, bv, bv, bv};
        #pragma unroll
        for (int ks = 0; ks < 4; ++ks) {
            half8 af = *(const half8*)&y_t[rt * 16 + m][q * 8 + ks * 32];
            acc = __builtin_amdgcn_mfma_f32_16x16x32_f16(af, bfr[ks], acc, 0, 0, 0);
        }
        #pragma unroll
        for (int reg = 0; reg < 4; ++reg)
            o_t[q * 4 + reg][h * 16 + m] = acc[reg];
        __syncthreads();
        int r = tid >> 5, c4 = tid & 31;       // 16 rows x 32 float4 = 512 thr
        int grow = rt * 16 + r;
        if (grow < cnt)
            *(float4*)(out + ((size_t)(off + grow) << 7) + c4 * 4) = *(const float4*)&o_t[r][c4 * 4];
        __syncthreads();
    }
}

extern "C" void kernel_launch(void* const* d_in, const int* in_sizes, int n_in,
                              void* d_out, int out_size, void* d_ws, size_t ws_size,
                              hipStream_t stream) {
    const float* x     = (const float*)d_in[0];
    const float* Wqkv  = (const float*)d_in[1];
    const float* Wproj = (const float*)d_in[2];
    const float* bproj = (const float*)d_in[3];
    const int*   offsets = (const int*)d_in[4];
    const int*   counts  = (const int*)d_in[5];

    int N = in_sizes[0] / 128;

    char* ws = (char*)d_ws;
    float* kv_t = (float*)ws;                                    ws += (size_t)MWIN * HH * 256 * 4;
    float* s    = (float*)ws;                                    ws += (size_t)MWIN * HH * 16 * 4;
    _Float16* q_h    = (_Float16*)ws;                            ws += (size_t)N * 128 * 2;
    _Float16* fq     = (_Float16*)ws;                            ws += (size_t)6144 * 8 * 2;
    _Float16* fp     = (_Float16*)ws;                            ws += (size_t)2048 * 8 * 2;
    float* out  = (float*)d_out;

    k_prep_w<<<32, 256, 0, stream>>>(Wqkv, Wproj, fq, fp);

    k_qkv_win<<<MWIN, 512, 0, stream>>>(x, (const half8*)fq, offsets, counts,
                                        q_h, kv_t, s);

    k_attn_proj<<<MWIN, 512, 0, stream>>>(q_h, kv_t, s, (const half8*)fp, bproj,
                                          offsets, counts, out);
}

// Round 13
// 145.637 us; speedup vs baseline: 1.4790x; 1.4790x over previous
//
#include <hip/hip_runtime.h>

#define MWIN 2048
#define HH 8

typedef _Float16 half8 __attribute__((ext_vector_type(8)));
typedef _Float16 half4 __attribute__((ext_vector_type(4)));
typedef float f32x4 __attribute__((ext_vector_type(4)));

// XCD-chunked window swizzle: 3x3 pooling neighbors (w +-1, +-32) stay in the
// same XCD L2 for both producer and consumer kernels.
__device__ __forceinline__ int win_swz(int bid) {
    return (bid & 7) * 256 + (bid >> 3);
}

// ---- weight prep: fragmentize Wqkv/Wproj fp32 -> MFMA-fragment fp16.
__global__ __launch_bounds__(256) void k_prep_w(const float* __restrict__ Wqkv,
                                                const float* __restrict__ Wproj,
                                                _Float16* __restrict__ fq,
                                                _Float16* __restrict__ fp) {
    int tid = blockIdx.x * 256 + threadIdx.x;
    const float* src;
    _Float16* dst;
    if (tid < 6144) { src = Wqkv; dst = fq; }
    else {
        tid -= 6144;
        if (tid >= 2048) return;
        src = Wproj; dst = fp;
    }
    int lane = tid & 63, r = tid >> 6;
    int ct = r & 3, ks = (r >> 2) & 3, cg = r >> 4;
    int m = lane & 15, q = lane >> 4;
    const float* s_ = src + (size_t)(cg * 64 + ct * 16 + m) * 128 + q * 8 + ks * 32;
    float4 f0 = *(const float4*)s_;
    float4 f1 = *(const float4*)(s_ + 4);
    half8 h;
    h[0] = (_Float16)f0.x; h[1] = (_Float16)f0.y; h[2] = (_Float16)f0.z; h[3] = (_Float16)f0.w;
    h[4] = (_Float16)f1.x; h[5] = (_Float16)f1.y; h[6] = (_Float16)f1.z; h[7] = (_Float16)f1.w;
    *(half8*)(dst + (size_t)tid * 8) = h;
}

// ---- per-window fused QKV GEMM + kv/s reduction ----
// ROUND-12 (rerun; r12 bench was an infra failure, no data): round-11's LDS
// lifetime overlay (36.9KB -> 4 blocks/CU cap) WITHOUT the forced (512,8)
// launch bound. r11's regression was pure register-force spill (VGPR_Count
// 32, 310MB scratch traffic); natural allocation for this register structure
// is ~52-65 (r6 measured 52), which permits 8 waves/SIMD without spilling.
// Col-tile mapping ctg = j*8 + h: j=0 emits ALL of q (xs dead, frags in
// regs), j=1 all k, j=2 all v, so one 36.9KB buffer serves xs -> q_lds ->
// kT/vT in sequence, barrier-separated.
__global__ __launch_bounds__(512) void k_qkv_win(const float* __restrict__ x,
                                                 const half8* __restrict__ fq,
                                                 const int* __restrict__ offsets,
                                                 const int* __restrict__ counts,
                                                 _Float16* __restrict__ q_h,
                                                 float* __restrict__ kv_t,
                                                 float* __restrict__ s) {
    // 36864B overlay buffer:
    //   phase A: xs[48][136]      (13056B)  stage -> frag-read
    //   phase Q: q_lds[48][136]   (13056B)  j0 write -> global store
    //   phase KV: kT[8][16][72] @0, vT[8][16][72] @9216 halfs (36864B)
    __shared__ __attribute__((aligned(16))) _Float16 ubuf[18432];
    _Float16 (*xs)[136]    = (_Float16(*)[136])ubuf;
    _Float16 (*q_lds)[136] = (_Float16(*)[136])ubuf;
    _Float16 (*kT)[16][72] = (_Float16(*)[16][72])ubuf;
    _Float16 (*vT)[16][72] = (_Float16(*)[16][72])(ubuf + 9216);

    int w = win_swz(blockIdx.x);
    int off = offsets[w], cnt = counts[w];
    int tid = threadIdx.x;

    // ---- phase A: cooperative coalesced stage of x (48 rows x 32 float4) ----
    #pragma unroll
    for (int it = 0; it < 3; ++it) {
        int j = it * 512 + tid;
        int row = j >> 5, c4 = j & 31;
        int sr = row < cnt ? row : cnt - 1;
        float4 f = *(const float4*)(x + (size_t)(off + sr) * 128 + c4 * 4);
        half4 hv;
        hv[0] = (_Float16)f.x; hv[1] = (_Float16)f.y;
        hv[2] = (_Float16)f.z; hv[3] = (_Float16)f.w;
        *(half4*)&xs[row][c4 * 4] = hv;
    }
    __syncthreads();                       // bar1: xs ready

    int h = tid >> 6, lane = tid & 63;
    int m = lane & 15, q = lane >> 4;

    // A fragments from LDS into registers
    half8 a[3][4];
    #pragma unroll
    for (int rt = 0; rt < 3; ++rt)
        #pragma unroll
        for (int ks = 0; ks < 4; ++ks)
            a[rt][ks] = *(const half8*)&xs[rt * 16 + m][q * 8 + ks * 32];
    __syncthreads();                       // bar2: xs dead, buffer reusable

    // ---- GEMM: j=0 -> q (all waves), j=1 -> k, j=2 -> v ----
    #pragma unroll
    for (int j = 0; j < 3; ++j) {
        int ctg = j * 8 + h;
        int cg = ctg >> 2, ctl = ctg & 3;
        f32x4 acc0 = {}, acc1 = {}, acc2 = {};
        #pragma unroll
        for (int ks = 0; ks < 4; ++ks) {
            half8 bfr = fq[((size_t)cg * 16 + ks * 4 + ctl) * 64 + lane];
            acc0 = __builtin_amdgcn_mfma_f32_16x16x32_f16(a[0][ks], bfr, acc0, 0, 0, 0);
            acc1 = __builtin_amdgcn_mfma_f32_16x16x32_f16(a[1][ks], bfr, acc1, 0, 0, 0);
            acc2 = __builtin_amdgcn_mfma_f32_16x16x32_f16(a[2][ks], bfr, acc2, 0, 0, 0);
        }
        if (j == 0) {
            // q: relu, row-major into q_lds (overlay; xs dead)
            #pragma unroll
            for (int reg = 0; reg < 4; ++reg) {
                q_lds[q * 4 + reg][h * 16 + m]      = (_Float16)fmaxf(acc0[reg], 0.f);
                q_lds[16 + q * 4 + reg][h * 16 + m] = (_Float16)fmaxf(acc1[reg], 0.f);
                q_lds[32 + q * 4 + reg][h * 16 + m] = (_Float16)fmaxf(acc2[reg], 0.f);
            }
            __syncthreads();               // bar3: q_lds complete
            // relu'd q rows -> global (coalesced half8)
            #pragma unroll
            for (int it = 0; it < 2; ++it) {
                int idx = it * 512 + tid;
                int row = idx >> 4, c8 = idx & 15;
                if (row < cnt)
                    *(half8*)(q_h + (size_t)(off + row) * 128 + c8 * 8) =
                        *(const half8*)&q_lds[row][c8 * 8];
            }
            __syncthreads();               // bar4: q_lds dead, kT/vT may write
        } else if (j == 1) {
            // k: relu + zero rows >= cnt, transposed kT[h][d][p]
            #pragma unroll
            for (int rt = 0; rt < 3; ++rt) {
                f32x4 acc = rt == 0 ? acc0 : (rt == 1 ? acc1 : acc2);
                int p0 = rt * 16 + q * 4;
                half4 hv;
                #pragma unroll
                for (int reg = 0; reg < 4; ++reg)
                    hv[reg] = (_Float16)((p0 + reg < cnt) ? fmaxf(acc[reg], 0.f) : 0.f);
                *(half4*)&kT[h][m][p0] = hv;
            }
            // wave-local zero-fill of kT[h] p 48..63
            {
                int zd = lane >> 2, zp = 48 + (lane & 3) * 4;
                *(half4*)&kT[h][zd][zp] = (half4){};
            }
        } else {
            // v: transposed vT[h][e][p]
            #pragma unroll
            for (int rt = 0; rt < 3; ++rt) {
                f32x4 acc = rt == 0 ? acc0 : (rt == 1 ? acc1 : acc2);
                int p0 = rt * 16 + q * 4;
                half4 hv;
                #pragma unroll
                for (int reg = 0; reg < 4; ++reg) hv[reg] = (_Float16)acc[reg];
                *(half4*)&vT[h][m][p0] = hv;
            }
            {
                int zd = lane >> 2, zp = 48 + (lane & 3) * 4;
                *(half4*)&vT[h][zd][zp] = (half4){};
            }
        }
    }

    // ---- kv = K^T V, s = K^T 1 via MFMA; wave h = head h (wave-local LDS) ----
    half8 a1 = *(const half8*)&kT[h][m][q * 8];
    half8 a2 = *(const half8*)&kT[h][m][32 + q * 8];
    half8 b1 = *(const half8*)&vT[h][m][q * 8];
    half8 b2 = *(const half8*)&vT[h][m][32 + q * 8];
    half8 ones;
    #pragma unroll
    for (int i = 0; i < 8; ++i) ones[i] = (_Float16)1.0f;
    f32x4 kva = {};
    kva = __builtin_amdgcn_mfma_f32_16x16x32_f16(a1, b1, kva, 0, 0, 0);
    kva = __builtin_amdgcn_mfma_f32_16x16x32_f16(a2, b2, kva, 0, 0, 0);
    f32x4 sa4 = {};
    sa4 = __builtin_amdgcn_mfma_f32_16x16x32_f16(a1, ones, sa4, 0, 0, 0);
    sa4 = __builtin_amdgcn_mfma_f32_16x16x32_f16(a2, ones, sa4, 0, 0, 0);
    *(f32x4*)(kv_t + (((size_t)(w * HH + h)) << 8) + m * 16 + q * 4) = kva;
    if (m == 0)
        *(f32x4*)(s + (((size_t)(w * HH + h)) << 4) + q * 4) = sa4;
}

// ---------------- fused attn + 3x3 pool + output projection ----------------
// (unchanged from round 10 so the qkv delta is attributable)
__global__ __launch_bounds__(512) void k_attn_proj(const _Float16* __restrict__ q_h,
                                                   const float* __restrict__ kv_t,
                                                   const float* __restrict__ s,
                                                   const half8* __restrict__ fp,
                                                   const float* __restrict__ bproj,
                                                   const int* __restrict__ offsets,
                                                   const int* __restrict__ counts,
                                                   float* __restrict__ out) {
    __shared__ _Float16 q_s[48][136];
    __shared__ _Float16 y_t[48][136];
    __shared__ float o_t[16][132];
    int w = win_swz(blockIdx.x);
    int h = threadIdx.x >> 6;
    int lane = threadIdx.x & 63;
    int col = lane & 15;
    int kq = lane >> 4;
    int off = offsets[w], cnt = counts[w];
    bool klive = kq < 2;
    int koff = (kq & 1) * 8;
    int tid = threadIdx.x;

    // coalesced stage of q rows (clamped at cnt-1 so attention needs no clamp)
    #pragma unroll
    for (int it = 0; it < 2; ++it) {
        int j = it * 512 + tid;
        int row = j >> 4, c8 = j & 15;
        if (row < 48) {
            int sr = row < cnt ? row : cnt - 1;
            *(half8*)&q_s[row][c8 * 8] =
                *(const half8*)(q_h + (size_t)(off + sr) * 128 + c8 * 8);
        }
    }

    // 3x3 pool into fp32 regs (overlaps the q staging; no barrier needed yet)
    int b = w >> 10, yy = (w >> 5) & 31, xx = w & 31;
    f32x4 k0 = {}, k1 = {}, s0 = {}, s1 = {};
    if (klive) {
        #pragma unroll
        for (int dy = -1; dy <= 1; ++dy)
            #pragma unroll
            for (int dx = -1; dx <= 1; ++dx) {
                int ny = yy + dy, nx = xx + dx;
                if (ny < 0 || ny >= 32 || nx < 0 || nx >= 32) continue;
                int nw = (b << 10) | (ny << 5) | nx;
                const float* kb = kv_t + (((size_t)(nw * HH + h)) << 8) + col * 16 + koff;
                k0 += *(const f32x4*)kb;
                k1 += *(const f32x4*)(kb + 4);
                const float* sb = s + (((size_t)(nw * HH + h)) << 4) + koff;
                s0 += *(const f32x4*)sb;
                s1 += *(const f32x4*)(sb + 4);
            }
    }
    half8 a_kv, a_s;
    #pragma unroll
    for (int i = 0; i < 4; ++i) {
        a_kv[i] = (_Float16)k0[i]; a_kv[4 + i] = (_Float16)k1[i];
        a_s[i]  = (_Float16)s0[i]; a_s[4 + i]  = (_Float16)s1[i];
    }
    __syncthreads();   // q_s ready

    #pragma unroll
    for (int c = 0; c < 3; ++c) {
        int p = c * 16 + col;
        half8 b_q = *(const half8*)&q_s[p][h * 16 + koff];
        f32x4 acc = {};
        acc = __builtin_amdgcn_mfma_f32_16x16x32_f16(a_kv, b_q, acc, 0, 0, 0);
        f32x4 accs = {};
        accs = __builtin_amdgcn_mfma_f32_16x16x32_f16(a_s, b_q, accs, 0, 0, 0);
        float zinv = 1.f / (accs[0] + 1e-6f);
        half4 yo;
        #pragma unroll
        for (int i = 0; i < 4; ++i) yo[i] = (_Float16)(acc[i] * zinv);
        *(half4*)&y_t[p][h * 16 + kq * 4] = yo;
    }
    __syncthreads();

    // projection: wave h owns output col-tile h; one 16-row band per step
    int m = col, q = kq;
    int cg = h >> 2, ctl = h & 3;
    half8 bfr[4];
    #pragma unroll
    for (int ks = 0; ks < 4; ++ks)
        bfr[ks] = fp[((size_t)cg * 16 + ks * 4 + ctl) * 64 + lane];
    float bv = bproj[h * 16 + m];
    #pragma unroll
    for (int rt = 0; rt < 3; ++rt) {
        f32x4 acc = (f32x4){bv, bv, bv, bv};
        #pragma unroll
        for (int ks = 0; ks < 4; ++ks) {
            half8 af = *(const half8*)&y_t[rt * 16 + m][q * 8 + ks * 32];
            acc = __builtin_amdgcn_mfma_f32_16x16x32_f16(af, bfr[ks], acc, 0, 0, 0);
        }
        #pragma unroll
        for (int reg = 0; reg < 4; ++reg)
            o_t[q * 4 + reg][h * 16 + m] = acc[reg];
        __syncthreads();
        int r = tid >> 5, c4 = tid & 31;       // 16 rows x 32 float4 = 512 thr
        int grow = rt * 16 + r;
        if (grow < cnt)
            *(float4*)(out + ((size_t)(off + grow) << 7) + c4 * 4) = *(const float4*)&o_t[r][c4 * 4];
        __syncthreads();
    }
}

extern "C" void kernel_launch(void* const* d_in, const int* in_sizes, int n_in,
                              void* d_out, int out_size, void* d_ws, size_t ws_size,
                              hipStream_t stream) {
    const float* x     = (const float*)d_in[0];
    const float* Wqkv  = (const float*)d_in[1];
    const float* Wproj = (const float*)d_in[2];
    const float* bproj = (const float*)d_in[3];
    const int*   offsets = (const int*)d_in[4];
    const int*   counts  = (const int*)d_in[5];

    int N = in_sizes[0] / 128;

    char* ws = (char*)d_ws;
    float* kv_t = (float*)ws;                                    ws += (size_t)MWIN * HH * 256 * 4;
    float* s    = (float*)ws;                                    ws += (size_t)MWIN * HH * 16 * 4;
    _Float16* q_h    = (_Float16*)ws;                            ws += (size_t)N * 128 * 2;
    _Float16* fq     = (_Float16*)ws;                            ws += (size_t)6144 * 8 * 2;
    _Float16* fp     = (_Float16*)ws;                            ws += (size_t)2048 * 8 * 2;
    float* out  = (float*)d_out;

    k_prep_w<<<32, 256, 0, stream>>>(Wqkv, Wproj, fq, fp);

    k_qkv_win<<<MWIN, 512, 0, stream>>>(x, (const half8*)fq, offsets, counts,
                                        q_h, kv_t, s);

    k_attn_proj<<<MWIN, 512, 0, stream>>>(q_h, kv_t, s, (const half8*)fp, bproj,
                                          offsets, counts, out);
}